// Round 14
// baseline (186.464 us; speedup 1.0000x reference)
//
#include <hip/hip_runtime.h>

#define F 128
#define CAP 32   // per-node bucket capacity; P(deg>=32) ~ 1e-13/node for Binomial(6e5, 1e-5)
#define CSH 4    // cnt padding shift: one counter per 64B line (16 ints)

typedef _Float16 f16x8 __attribute__((ext_vector_type(8)));
typedef float f32x4 __attribute__((ext_vector_type(4)));

// ---------------- kernel 1: MFMA GEMM, self-contained ----------------
// Loads raw W1, swizzles to fp16 fragments in LDS, computes Yb = f16(X @ W1) (unscaled),
// and zeroes this block's slice of the PADDED cnt array (16 ints/node, 6.4MB).
__global__ __launch_bounds__(256) void k_gemm_mfma(const float* __restrict__ X,
                                                   const float* __restrict__ W1,
                                                   int* __restrict__ cnt,
                                                   _Float16* __restrict__ Yb, int N) {
    __shared__ _Float16 Bs[F * F];   // 32 KB, swizzled fragment layout

    int tid = threadIdx.x;
    int g = blockIdx.x;

    // zero padded cnt slice: 2048 ints/block (8/thread, two int4 stores), coalesced
    {
        int total = N << CSH;
        int base = g * 2048 + tid * 8;
        if (base + 7 < total) {
            *(int4*)&cnt[base]     = make_int4(0, 0, 0, 0);
            *(int4*)&cnt[base + 4] = make_int4(0, 0, 0, 0);
        } else {
            for (int j = base; j < total; ++j) cnt[j] = 0;
        }
    }

    // cooperative W1 -> LDS swizzle
    {
        int krow = tid >> 1;
        int n0 = (tid & 1) * 64;
        int t = krow >> 5, j = krow & 7, qa = (krow >> 3) & 3;
        const float* wp = &W1[krow * F + n0];
#pragma unroll
        for (int q4 = 0; q4 < 16; ++q4) {
            float4 w = *(const float4*)(wp + q4 * 4);
            int n = n0 + q4 * 4;
            int c = n >> 4;
            int m = n & 15;
            int ob = (t * 8 + c) * 512 + j;
            Bs[ob + (qa * 16 + m + 0) * 8] = (_Float16)w.x;
            Bs[ob + (qa * 16 + m + 1) * 8] = (_Float16)w.y;
            Bs[ob + (qa * 16 + m + 2) * 8] = (_Float16)w.z;
            Bs[ob + (qa * 16 + m + 3) * 8] = (_Float16)w.w;
        }
    }
    __syncthreads();

    int lane = tid & 63, wave = tid >> 6;
    int quad = lane >> 4, m = lane & 15;
    int r0 = g * 128 + wave * 32;

    f32x4 acc[2][8];
#pragma unroll
    for (int rt = 0; rt < 2; ++rt)
#pragma unroll
        for (int c = 0; c < 8; ++c) acc[rt][c] = (f32x4)0.0f;

    int ra = r0 + m;      if (ra >= N) ra = N - 1;
    int rb = r0 + 16 + m; if (rb >= N) rb = N - 1;
    const float* pxa = &X[(size_t)ra * F + quad * 8];
    const float* pxb = &X[(size_t)rb * F + quad * 8];

    float4 a0 = *(const float4*)pxa, a1 = *(const float4*)(pxa + 4);
    float4 a2 = *(const float4*)pxb, a3 = *(const float4*)(pxb + 4);

#pragma unroll 1
    for (int t = 0; t < 4; ++t) {
        const _Float16* bp = &Bs[t * 4096 + lane * 8];
        f16x8 B[8];
#pragma unroll
        for (int c = 0; c < 8; ++c) B[c] = *(const f16x8*)(bp + c * 512);

        float fa[8] = {a0.x, a0.y, a0.z, a0.w, a1.x, a1.y, a1.z, a1.w};
        float fb[8] = {a2.x, a2.y, a2.z, a2.w, a3.x, a3.y, a3.z, a3.w};
        f16x8 A0, A1;
#pragma unroll
        for (int j = 0; j < 8; ++j) {
            A0[j] = (_Float16)fa[j];
            A1[j] = (_Float16)fb[j];
        }
        if (t < 3) {
            a0 = *(const float4*)(pxa + (t + 1) * 32);
            a1 = *(const float4*)(pxa + (t + 1) * 32 + 4);
            a2 = *(const float4*)(pxb + (t + 1) * 32);
            a3 = *(const float4*)(pxb + (t + 1) * 32 + 4);
        }
#pragma unroll
        for (int c = 0; c < 8; ++c) {
            acc[0][c] = __builtin_amdgcn_mfma_f32_16x16x32_f16(A0, B[c], acc[0][c], 0, 0, 0);
            acc[1][c] = __builtin_amdgcn_mfma_f32_16x16x32_f16(A1, B[c], acc[1][c], 0, 0, 0);
        }
    }

#pragma unroll
    for (int rt = 0; rt < 2; ++rt) {
        int rbase = r0 + rt * 16 + quad * 4;
#pragma unroll
        for (int rr = 0; rr < 4; ++rr) {
            int row = rbase + rr;
            if (row < N) {
#pragma unroll
                for (int c = 0; c < 8; ++c)
                    Yb[(size_t)row * F + c * 16 + m] = (_Float16)acc[rt][c][rr];
            }
        }
    }
}

// ---------------- kernel 2: prep ----------------
// block 0: w2l/cconst; blocks 1..bG: gstart binary search; rest: bucket-CSR edge fill
// with PADDED counters (one per 64B line) -> no same-line atomic serialization.
__global__ __launch_bounds__(256) void k_prep(const float* __restrict__ W2, const float* __restrict__ Wlin,
                                              const float* __restrict__ b2, const float* __restrict__ blin,
                                              const int* __restrict__ batch,
                                              const int* __restrict__ src, const int* __restrict__ dst,
                                              float* __restrict__ w2l, float* __restrict__ cconst,
                                              int* __restrict__ gstart, int* __restrict__ cnt,
                                              int* __restrict__ srcs, int N, int E, int G, int bG) {
    int bid = blockIdx.x;
    int tid = threadIdx.x;
    if (bid == 0) {
        __shared__ float sh[F];
        if (tid < F) {
            float s = 0.0f;
            for (int j = 0; j < F; j += 4) {
                float4 w = *(const float4*)&W2[tid * F + j];
                float4 l = *(const float4*)&Wlin[j];
                s += w.x * l.x + w.y * l.y + w.z * l.z + w.w * l.w;
            }
            w2l[tid] = s;
            sh[tid] = b2[tid] * Wlin[tid];
        }
        __syncthreads();
        if (tid == 0) {
            float c = blin[0];
            for (int j = 0; j < F; ++j) c += sh[j];
            *cconst = c;
        }
    } else if (bid <= bG) {
        int g = (bid - 1) * 256 + tid;
        if (g < G) {
            int lo = 0, hi = N;
            while (lo < hi) { int mid = (lo + hi) >> 1; if (batch[mid] < g) lo = mid + 1; else hi = mid; }
            gstart[g] = lo;
            if (g == 0) gstart[G] = N;
        }
    } else {
        int e = (bid - 1 - bG) * 256 + tid;
        if (e < E) {
            int s = src[e], d = dst[e];
            int slot = atomicAdd(&cnt[d << CSH], 1);
            if (slot < CAP) srcs[d * CAP + slot] = s;
        }
    }
}

// ---------------- kernel 3: layer-1 aggregation, 16 lanes/node, SRC-SORTED buckets ------
// (R13-proven) counters read from padded array: cnt[n<<CSH].
__global__ __launch_bounds__(256) void k_agg_z(const _Float16* __restrict__ hWb,
                                               const int* __restrict__ cnt, const int* __restrict__ srcs,
                                               const float* __restrict__ bias, const float* __restrict__ w2l,
                                               float* __restrict__ zt, int N) {
    __shared__ int sdeg[16], snode[16], smapN[16], smapD[16];
    __shared__ int sbuck[16][CAP];   // raw bucket
    __shared__ int ssort[16][CAP];   // src-sorted bucket
    int tid = threadIdx.x;
    int nb = blockIdx.x * 16;
    if (tid < 16) {
        int n = nb + tid;
        sdeg[tid]  = (n < N) ? cnt[n << CSH] : 0x40000000;
        snode[tid] = (n < N) ? n : -1;
    }
    __syncthreads();
    if (tid < 16) {
        int v = sdeg[tid];
        int rank = 0;
#pragma unroll
        for (int j = 0; j < 16; ++j) {
            int vj = sdeg[j];
            rank += (vj < v) || (vj == v && j < tid);
        }
        smapN[rank] = snode[tid];
        smapD[rank] = sdeg[tid];
    }
    __syncthreads();
    int ln = tid >> 4;                    // local node slot 0..15
    int lane = tid & 15;                  // 16 lanes/node, 8 elems/lane
    int node = smapN[ln];
    int dg = smapD[ln];
    bool valid = (node >= 0);
    int nodeSafe = valid ? node : 0;
    int du = valid ? min(dg, CAP) : 0;

    // load bucket into LDS (2 entries/lane max)
    if (lane < du)      sbuck[ln][lane]      = srcs[nodeSafe * CAP + lane];
    if (lane + 16 < du) sbuck[ln][lane + 16] = srcs[nodeSafe * CAP + lane + 16];
    __syncthreads();

    // rank-sort bucket by src id (du <= 32; 2 entries/lane)
    {
        if (lane < du) {
            int k = sbuck[ln][lane];
            int r = 0;
            for (int j = 0; j < du; ++j) {
                int kj = sbuck[ln][j];
                r += (kj < k) || (kj == k && j < lane);
            }
            ssort[ln][r] = k;
        }
        if (lane + 16 < du) {
            int i1 = lane + 16;
            int k = sbuck[ln][i1];
            int r = 0;
            for (int j = 0; j < du; ++j) {
                int kj = sbuck[ln][j];
                r += (kj < k) || (kj == k && j < i1);
            }
            ssort[ln][r] = k;
        }
    }
    __syncthreads();

    float di = rsqrtf((float)dg + 1.0f);
    float s[8];
    {
        f16x8 v0 = *(const f16x8*)&hWb[(size_t)nodeSafe * F + lane * 8];
#pragma unroll
        for (int j = 0; j < 8; ++j) s[j] = di * (float)v0[j];
    }
    int e = 0;
    for (; e + 4 <= du; e += 4) {
        int i0 = ssort[ln][e], i1 = ssort[ln][e + 1], i2 = ssort[ln][e + 2], i3 = ssort[ln][e + 3];
        float w0 = rsqrtf((float)cnt[i0 << CSH] + 1.0f);
        float w1 = rsqrtf((float)cnt[i1 << CSH] + 1.0f);
        float w2 = rsqrtf((float)cnt[i2 << CSH] + 1.0f);
        float w3 = rsqrtf((float)cnt[i3 << CSH] + 1.0f);
        f16x8 a0 = *(const f16x8*)&hWb[(size_t)i0 * F + lane * 8];
        f16x8 a1 = *(const f16x8*)&hWb[(size_t)i1 * F + lane * 8];
        f16x8 a2 = *(const f16x8*)&hWb[(size_t)i2 * F + lane * 8];
        f16x8 a3 = *(const f16x8*)&hWb[(size_t)i3 * F + lane * 8];
#pragma unroll
        for (int j = 0; j < 8; ++j) {
            s[j] = fmaf(w0, (float)a0[j], s[j]);
            s[j] = fmaf(w1, (float)a1[j], s[j]);
            s[j] = fmaf(w2, (float)a2[j], s[j]);
            s[j] = fmaf(w3, (float)a3[j], s[j]);
        }
    }
    for (; e < du; ++e) {
        int i0 = ssort[ln][e];
        float w0 = rsqrtf((float)cnt[i0 << CSH] + 1.0f);
        f16x8 v0 = *(const f16x8*)&hWb[(size_t)i0 * F + lane * 8];
#pragma unroll
        for (int j = 0; j < 8; ++j) s[j] = fmaf(w0, (float)v0[j], s[j]);
    }
    float p = 0.0f;
    {
        float4 bb0 = *(const float4*)&bias[lane * 8];
        float4 bb1 = *(const float4*)&bias[lane * 8 + 4];
        float4 ww0 = *(const float4*)&w2l[lane * 8];
        float4 ww1 = *(const float4*)&w2l[lane * 8 + 4];
        p += fmaxf(fmaf(di, s[0], bb0.x), 0.0f) * ww0.x;
        p += fmaxf(fmaf(di, s[1], bb0.y), 0.0f) * ww0.y;
        p += fmaxf(fmaf(di, s[2], bb0.z), 0.0f) * ww0.z;
        p += fmaxf(fmaf(di, s[3], bb0.w), 0.0f) * ww0.w;
        p += fmaxf(fmaf(di, s[4], bb1.x), 0.0f) * ww1.x;
        p += fmaxf(fmaf(di, s[5], bb1.y), 0.0f) * ww1.y;
        p += fmaxf(fmaf(di, s[6], bb1.z), 0.0f) * ww1.z;
        p += fmaxf(fmaf(di, s[7], bb1.w), 0.0f) * ww1.w;
    }
#pragma unroll
    for (int d = 1; d < 16; d <<= 1) p += __shfl_xor(p, d);
    if (valid && lane == 0) zt[node] = di * p;
}

// ---------------- kernel 4: layer-2 aggregation + mean-pool ----------
__global__ __launch_bounds__(256) void k_pool(const float* __restrict__ zt,
                                              const int* __restrict__ cnt, const int* __restrict__ srcs,
                                              const int* __restrict__ gstart, const float* __restrict__ cconst,
                                              const float* __restrict__ blin, float* __restrict__ out, int G) {
    int g = blockIdx.x;
    int g0 = gstart[g], g1 = gstart[g + 1];
    float acc = 0.0f;
    for (int n = g0 + threadIdx.x; n < g1; n += 256) {
        float s = zt[n];
        int dg = cnt[n << CSH];
        int du = min(dg, CAP);
        int e0 = n * CAP, e1 = e0 + du;
        int e = e0;
        for (; e + 4 <= e1; e += 4) {
            s += zt[srcs[e]] + zt[srcs[e + 1]] + zt[srcs[e + 2]] + zt[srcs[e + 3]];
        }
        for (; e < e1; ++e) s += zt[srcs[e]];
        acc += rsqrtf((float)dg + 1.0f) * s;
    }
#pragma unroll
    for (int d = 1; d < 64; d <<= 1) acc += __shfl_xor(acc, d);
    __shared__ float ws4[4];
    if ((threadIdx.x & 63) == 0) ws4[threadIdx.x >> 6] = acc;
    __syncthreads();
    if (threadIdx.x == 0) {
        float sum = ws4[0] + ws4[1] + ws4[2] + ws4[3];
        int c = g1 - g0;
        out[g] = (c > 0) ? (sum / (float)c + cconst[0]) : blin[0];
    }
}

// ---------------- launch ----------------

extern "C" void kernel_launch(void* const* d_in, const int* in_sizes, int n_in,
                              void* d_out, int out_size, void* d_ws, size_t ws_size,
                              hipStream_t stream) {
    const float* x    = (const float*)d_in[0];
    const int*   ei   = (const int*)d_in[1];
    const int*   batch= (const int*)d_in[2];
    const float* W1   = (const float*)d_in[3];
    const float* b1   = (const float*)d_in[4];
    const float* W2   = (const float*)d_in[5];
    const float* b2   = (const float*)d_in[6];
    const float* Wlin = (const float*)d_in[7];
    const float* blin = (const float*)d_in[8];
    float* out = (float*)d_out;

    const int N = in_sizes[2];          // 100000
    const int E = in_sizes[1] / 2;      // 600000
    const int G = out_size;             // 512
    const int* src = ei;
    const int* dst = ei + E;

    char* p = (char*)d_ws;
    auto take = [&](size_t bytes) { char* q = p; p += (bytes + 255) & ~(size_t)255; return q; };
    _Float16* hWb  = (_Float16*)take((size_t)N * F * 2);      // f16( x @ W1 ), unscaled
    float*  ztbuf  = (float*)take((size_t)N * 4);
    int*    cnt    = (int*)  take(((size_t)N << CSH) * 4);    // PADDED indegree: 1 counter / 64B line
    int*    srcs   = (int*)  take((size_t)N * CAP * 4);       // padded bucket CSR (12.8 MB)
    int*    gstart = (int*)  take((size_t)(G + 1) * 4);
    float*  w2l    = (float*)take((size_t)F * 4);
    float*  cconst = (float*)take(256);

    const int bG  = (G + 255) / 256;
    const int nbGemm = (N + 127) / 128;
    const int nbE = (E + 255) / 256;

    k_gemm_mfma<<<nbGemm, 256, 0, stream>>>(x, W1, cnt, hWb, N);
    k_prep <<<1 + bG + nbE, 256, 0, stream>>>(W2, Wlin, b2, blin, batch, src, dst,
                                              w2l, cconst, gstart, cnt, srcs, N, E, G, bG);
    k_agg_z<<<(N + 15) / 16, 256, 0, stream>>>(hWb, cnt, srcs, b1, w2l, ztbuf, N);
    k_pool <<<G, 256, 0, stream>>>(ztbuf, cnt, srcs, gstart, cconst, blin, out, G);
}

// Round 15
// 180.578 us; speedup vs baseline: 1.0326x; 1.0326x over previous
//
#include <hip/hip_runtime.h>

#define F 128
#define CAP 32   // per-node bucket capacity; P(deg>=32) ~ 1e-13/node for Binomial(6e5, 1e-5)

typedef _Float16 f16x8 __attribute__((ext_vector_type(8)));
typedef float f32x4 __attribute__((ext_vector_type(4)));

// ---------------- kernel 1: MFMA GEMM, self-contained (R13-proven) ----------------
__global__ __launch_bounds__(256) void k_gemm_mfma(const float* __restrict__ X,
                                                   const float* __restrict__ W1,
                                                   int* __restrict__ cnt,
                                                   _Float16* __restrict__ Yb, int N) {
    __shared__ _Float16 Bs[F * F];   // 32 KB, swizzled fragment layout

    int tid = threadIdx.x;
    int g = blockIdx.x;

    // zero compact cnt slice early
    int zrow = g * 128 + tid;
    if (tid < 128 && zrow < N) cnt[zrow] = 0;

    // cooperative W1 -> LDS swizzle
    {
        int krow = tid >> 1;
        int n0 = (tid & 1) * 64;
        int t = krow >> 5, j = krow & 7, qa = (krow >> 3) & 3;
        const float* wp = &W1[krow * F + n0];
#pragma unroll
        for (int q4 = 0; q4 < 16; ++q4) {
            float4 w = *(const float4*)(wp + q4 * 4);
            int n = n0 + q4 * 4;
            int c = n >> 4;
            int m = n & 15;
            int ob = (t * 8 + c) * 512 + j;
            Bs[ob + (qa * 16 + m + 0) * 8] = (_Float16)w.x;
            Bs[ob + (qa * 16 + m + 1) * 8] = (_Float16)w.y;
            Bs[ob + (qa * 16 + m + 2) * 8] = (_Float16)w.z;
            Bs[ob + (qa * 16 + m + 3) * 8] = (_Float16)w.w;
        }
    }
    __syncthreads();

    int lane = tid & 63, wave = tid >> 6;
    int quad = lane >> 4, m = lane & 15;
    int r0 = g * 128 + wave * 32;

    f32x4 acc[2][8];
#pragma unroll
    for (int rt = 0; rt < 2; ++rt)
#pragma unroll
        for (int c = 0; c < 8; ++c) acc[rt][c] = (f32x4)0.0f;

    int ra = r0 + m;      if (ra >= N) ra = N - 1;
    int rb = r0 + 16 + m; if (rb >= N) rb = N - 1;
    const float* pxa = &X[(size_t)ra * F + quad * 8];
    const float* pxb = &X[(size_t)rb * F + quad * 8];

    float4 a0 = *(const float4*)pxa, a1 = *(const float4*)(pxa + 4);
    float4 a2 = *(const float4*)pxb, a3 = *(const float4*)(pxb + 4);

#pragma unroll 1
    for (int t = 0; t < 4; ++t) {
        const _Float16* bp = &Bs[t * 4096 + lane * 8];
        f16x8 B[8];
#pragma unroll
        for (int c = 0; c < 8; ++c) B[c] = *(const f16x8*)(bp + c * 512);

        float fa[8] = {a0.x, a0.y, a0.z, a0.w, a1.x, a1.y, a1.z, a1.w};
        float fb[8] = {a2.x, a2.y, a2.z, a2.w, a3.x, a3.y, a3.z, a3.w};
        f16x8 A0, A1;
#pragma unroll
        for (int j = 0; j < 8; ++j) {
            A0[j] = (_Float16)fa[j];
            A1[j] = (_Float16)fb[j];
        }
        if (t < 3) {
            a0 = *(const float4*)(pxa + (t + 1) * 32);
            a1 = *(const float4*)(pxa + (t + 1) * 32 + 4);
            a2 = *(const float4*)(pxb + (t + 1) * 32);
            a3 = *(const float4*)(pxb + (t + 1) * 32 + 4);
        }
#pragma unroll
        for (int c = 0; c < 8; ++c) {
            acc[0][c] = __builtin_amdgcn_mfma_f32_16x16x32_f16(A0, B[c], acc[0][c], 0, 0, 0);
            acc[1][c] = __builtin_amdgcn_mfma_f32_16x16x32_f16(A1, B[c], acc[1][c], 0, 0, 0);
        }
    }

#pragma unroll
    for (int rt = 0; rt < 2; ++rt) {
        int rbase = r0 + rt * 16 + quad * 4;
#pragma unroll
        for (int rr = 0; rr < 4; ++rr) {
            int row = rbase + rr;
            if (row < N) {
#pragma unroll
                for (int c = 0; c < 8; ++c)
                    Yb[(size_t)row * F + c * 16 + m] = (_Float16)acc[rt][c][rr];
            }
        }
    }
}

// ---------------- kernel 2: prep with XCD-local dst-range binned fill ----------------
// block 0: w2l/cconst; blocks 1..bG: gstart; workers: group r = (w&7) handles ONLY edges
// with dst in range r (N/8-sized). Under round-robin dispatch, group r's blocks share an
// XCD -> bucket+cnt lines stay in ONE L2, the ~6 writes/line merge, writeback once.
// Partition-by-range is exactly-once regardless of physical mapping (G16-safe).
__global__ __launch_bounds__(256) void k_prep(const float* __restrict__ W2, const float* __restrict__ Wlin,
                                              const float* __restrict__ b2, const float* __restrict__ blin,
                                              const int* __restrict__ batch,
                                              const int* __restrict__ src, const int* __restrict__ dst,
                                              float* __restrict__ w2l, float* __restrict__ cconst,
                                              int* __restrict__ gstart, int* __restrict__ cnt,
                                              int* __restrict__ srcs, int N, int E, int G, int bG, int nW) {
    int bid = blockIdx.x;
    int tid = threadIdx.x;
    if (bid == 0) {
        __shared__ float sh[F];
        if (tid < F) {
            float s = 0.0f;
            for (int j = 0; j < F; j += 4) {
                float4 w = *(const float4*)&W2[tid * F + j];
                float4 l = *(const float4*)&Wlin[j];
                s += w.x * l.x + w.y * l.y + w.z * l.z + w.w * l.w;
            }
            w2l[tid] = s;
            sh[tid] = b2[tid] * Wlin[tid];
        }
        __syncthreads();
        if (tid == 0) {
            float c = blin[0];
            for (int j = 0; j < F; ++j) c += sh[j];
            *cconst = c;
        }
    } else if (bid <= bG) {
        int g = (bid - 1) * 256 + tid;
        if (g < G) {
            int lo = 0, hi = N;
            while (lo < hi) { int mid = (lo + hi) >> 1; if (batch[mid] < g) lo = mid + 1; else hi = mid; }
            gstart[g] = lo;
            if (g == 0) gstart[G] = N;
        }
    } else {
        int w = bid - 1 - bG;            // worker id, 0..nW-1, nW % 8 == 0
        int r = w & 7;                    // dst-range group (~ physical XCD via round-robin)
        int k = w >> 3;                   // rank within group
        int Wg = nW >> 3;                 // blocks per group
        int rngN = (N + 7) >> 3;
        int lo = r * rngN, hi = min(N, lo + rngN);
        const int CH = 1024;              // edges per chunk (4/thread)
        for (int e0 = k * CH; e0 < E; e0 += Wg * CH) {
            int e = e0 + tid;
#pragma unroll
            for (int it = 0; it < 4; ++it, e += 256) {
                if (e < E) {
                    int d = dst[e];
                    if (d >= lo && d < hi) {
                        int s = src[e];
                        int slot = atomicAdd(&cnt[d], 1);
                        if (slot < CAP) srcs[d * CAP + slot] = s;
                    }
                }
            }
        }
    }
}

// ---------------- kernel 3: layer-1 aggregation, 16 lanes/node, SRC-SORTED buckets ------
// (R13-proven)
__global__ __launch_bounds__(256) void k_agg_z(const _Float16* __restrict__ hWb,
                                               const int* __restrict__ cnt, const int* __restrict__ srcs,
                                               const float* __restrict__ bias, const float* __restrict__ w2l,
                                               float* __restrict__ zt, int N) {
    __shared__ int sdeg[16], snode[16], smapN[16], smapD[16];
    __shared__ int sbuck[16][CAP];   // raw bucket
    __shared__ int ssort[16][CAP];   // src-sorted bucket
    int tid = threadIdx.x;
    int nb = blockIdx.x * 16;
    if (tid < 16) {
        int n = nb + tid;
        sdeg[tid]  = (n < N) ? cnt[n] : 0x40000000;
        snode[tid] = (n < N) ? n : -1;
    }
    __syncthreads();
    if (tid < 16) {
        int v = sdeg[tid];
        int rank = 0;
#pragma unroll
        for (int j = 0; j < 16; ++j) {
            int vj = sdeg[j];
            rank += (vj < v) || (vj == v && j < tid);
        }
        smapN[rank] = snode[tid];
        smapD[rank] = sdeg[tid];
    }
    __syncthreads();
    int ln = tid >> 4;                    // local node slot 0..15
    int lane = tid & 15;                  // 16 lanes/node, 8 elems/lane
    int node = smapN[ln];
    int dg = smapD[ln];
    bool valid = (node >= 0);
    int nodeSafe = valid ? node : 0;
    int du = valid ? min(dg, CAP) : 0;

    // load bucket into LDS (2 entries/lane max)
    if (lane < du)      sbuck[ln][lane]      = srcs[nodeSafe * CAP + lane];
    if (lane + 16 < du) sbuck[ln][lane + 16] = srcs[nodeSafe * CAP + lane + 16];
    __syncthreads();

    // rank-sort bucket by src id (du <= 32; 2 entries/lane)
    {
        if (lane < du) {
            int k = sbuck[ln][lane];
            int r = 0;
            for (int j = 0; j < du; ++j) {
                int kj = sbuck[ln][j];
                r += (kj < k) || (kj == k && j < lane);
            }
            ssort[ln][r] = k;
        }
        if (lane + 16 < du) {
            int i1 = lane + 16;
            int k = sbuck[ln][i1];
            int r = 0;
            for (int j = 0; j < du; ++j) {
                int kj = sbuck[ln][j];
                r += (kj < k) || (kj == k && j < i1);
            }
            ssort[ln][r] = k;
        }
    }
    __syncthreads();

    float di = rsqrtf((float)dg + 1.0f);
    float s[8];
    {
        f16x8 v0 = *(const f16x8*)&hWb[(size_t)nodeSafe * F + lane * 8];
#pragma unroll
        for (int j = 0; j < 8; ++j) s[j] = di * (float)v0[j];
    }
    int e = 0;
    for (; e + 4 <= du; e += 4) {
        int i0 = ssort[ln][e], i1 = ssort[ln][e + 1], i2 = ssort[ln][e + 2], i3 = ssort[ln][e + 3];
        float w0 = rsqrtf((float)cnt[i0] + 1.0f);
        float w1 = rsqrtf((float)cnt[i1] + 1.0f);
        float w2 = rsqrtf((float)cnt[i2] + 1.0f);
        float w3 = rsqrtf((float)cnt[i3] + 1.0f);
        f16x8 a0 = *(const f16x8*)&hWb[(size_t)i0 * F + lane * 8];
        f16x8 a1 = *(const f16x8*)&hWb[(size_t)i1 * F + lane * 8];
        f16x8 a2 = *(const f16x8*)&hWb[(size_t)i2 * F + lane * 8];
        f16x8 a3 = *(const f16x8*)&hWb[(size_t)i3 * F + lane * 8];
#pragma unroll
        for (int j = 0; j < 8; ++j) {
            s[j] = fmaf(w0, (float)a0[j], s[j]);
            s[j] = fmaf(w1, (float)a1[j], s[j]);
            s[j] = fmaf(w2, (float)a2[j], s[j]);
            s[j] = fmaf(w3, (float)a3[j], s[j]);
        }
    }
    for (; e < du; ++e) {
        int i0 = ssort[ln][e];
        float w0 = rsqrtf((float)cnt[i0] + 1.0f);
        f16x8 v0 = *(const f16x8*)&hWb[(size_t)i0 * F + lane * 8];
#pragma unroll
        for (int j = 0; j < 8; ++j) s[j] = fmaf(w0, (float)v0[j], s[j]);
    }
    float p = 0.0f;
    {
        float4 bb0 = *(const float4*)&bias[lane * 8];
        float4 bb1 = *(const float4*)&bias[lane * 8 + 4];
        float4 ww0 = *(const float4*)&w2l[lane * 8];
        float4 ww1 = *(const float4*)&w2l[lane * 8 + 4];
        p += fmaxf(fmaf(di, s[0], bb0.x), 0.0f) * ww0.x;
        p += fmaxf(fmaf(di, s[1], bb0.y), 0.0f) * ww0.y;
        p += fmaxf(fmaf(di, s[2], bb0.z), 0.0f) * ww0.z;
        p += fmaxf(fmaf(di, s[3], bb0.w), 0.0f) * ww0.w;
        p += fmaxf(fmaf(di, s[4], bb1.x), 0.0f) * ww1.x;
        p += fmaxf(fmaf(di, s[5], bb1.y), 0.0f) * ww1.y;
        p += fmaxf(fmaf(di, s[6], bb1.z), 0.0f) * ww1.z;
        p += fmaxf(fmaf(di, s[7], bb1.w), 0.0f) * ww1.w;
    }
#pragma unroll
    for (int d = 1; d < 16; d <<= 1) p += __shfl_xor(p, d);
    if (valid && lane == 0) zt[node] = di * p;
}

// ---------------- kernel 4: layer-2 aggregation + mean-pool (R13-proven) ----------
__global__ __launch_bounds__(256) void k_pool(const float* __restrict__ zt,
                                              const int* __restrict__ cnt, const int* __restrict__ srcs,
                                              const int* __restrict__ gstart, const float* __restrict__ cconst,
                                              const float* __restrict__ blin, float* __restrict__ out, int G) {
    int g = blockIdx.x;
    int g0 = gstart[g], g1 = gstart[g + 1];
    float acc = 0.0f;
    for (int n = g0 + threadIdx.x; n < g1; n += 256) {
        float s = zt[n];
        int dg = cnt[n];
        int du = min(dg, CAP);
        int e0 = n * CAP, e1 = e0 + du;
        int e = e0;
        for (; e + 4 <= e1; e += 4) {
            s += zt[srcs[e]] + zt[srcs[e + 1]] + zt[srcs[e + 2]] + zt[srcs[e + 3]];
        }
        for (; e < e1; ++e) s += zt[srcs[e]];
        acc += rsqrtf((float)dg + 1.0f) * s;
    }
#pragma unroll
    for (int d = 1; d < 64; d <<= 1) acc += __shfl_xor(acc, d);
    __shared__ float ws4[4];
    if ((threadIdx.x & 63) == 0) ws4[threadIdx.x >> 6] = acc;
    __syncthreads();
    if (threadIdx.x == 0) {
        float sum = ws4[0] + ws4[1] + ws4[2] + ws4[3];
        int c = g1 - g0;
        out[g] = (c > 0) ? (sum / (float)c + cconst[0]) : blin[0];
    }
}

// ---------------- launch ----------------

extern "C" void kernel_launch(void* const* d_in, const int* in_sizes, int n_in,
                              void* d_out, int out_size, void* d_ws, size_t ws_size,
                              hipStream_t stream) {
    const float* x    = (const float*)d_in[0];
    const int*   ei   = (const int*)d_in[1];
    const int*   batch= (const int*)d_in[2];
    const float* W1   = (const float*)d_in[3];
    const float* b1   = (const float*)d_in[4];
    const float* W2   = (const float*)d_in[5];
    const float* b2   = (const float*)d_in[6];
    const float* Wlin = (const float*)d_in[7];
    const float* blin = (const float*)d_in[8];
    float* out = (float*)d_out;

    const int N = in_sizes[2];          // 100000
    const int E = in_sizes[1] / 2;      // 600000
    const int G = out_size;             // 512
    const int* src = ei;
    const int* dst = ei + E;

    char* p = (char*)d_ws;
    auto take = [&](size_t bytes) { char* q = p; p += (bytes + 255) & ~(size_t)255; return q; };
    _Float16* hWb  = (_Float16*)take((size_t)N * F * 2);  // f16( x @ W1 ), unscaled
    float*  ztbuf  = (float*)take((size_t)N * 4);
    int*    cnt    = (int*)  take((size_t)N * 4);          // compact indegree (no self-loop)
    int*    srcs   = (int*)  take((size_t)N * CAP * 4);    // padded bucket CSR (12.8 MB)
    int*    gstart = (int*)  take((size_t)(G + 1) * 4);
    float*  w2l    = (float*)take((size_t)F * 4);
    float*  cconst = (float*)take(256);

    const int bG  = (G + 255) / 256;
    const int nbGemm = (N + 127) / 128;
    const int nW = 2048;                 // fill workers, multiple of 8

    k_gemm_mfma<<<nbGemm, 256, 0, stream>>>(x, W1, cnt, hWb, N);
    k_prep <<<1 + bG + nW, 256, 0, stream>>>(W2, Wlin, b2, blin, batch, src, dst,
                                             w2l, cconst, gstart, cnt, srcs, N, E, G, bG, nW);
    k_agg_z<<<(N + 15) / 16, 256, 0, stream>>>(hWb, cnt, srcs, b1, w2l, ztbuf, N);
    k_pool <<<G, 256, 0, stream>>>(ztbuf, cnt, srcs, gstart, cconst, blin, out, G);
}